// Round 2
// baseline (79.536 us; speedup 1.0000x reference)
//
#include <hip/hip_runtime.h>
#include <hip/hip_bf16.h>
#include <math.h>

#define N_ROWS 8192
#define M_ROWS 4096
#define DDIM   512
#define SDIM   16

#define BM 256
#define BN 256
#define BK 32
#define NT (DDIM / BK)   // 16 K-tiles

typedef __attribute__((ext_vector_type(8))) __bf16 bf16x8;
typedef __attribute__((ext_vector_type(4))) float f32x4;

__device__ __forceinline__ unsigned short f2bf_rne(float f) {
  unsigned u = __float_as_uint(f);
  u += 0x7fffu + ((u >> 16) & 1u);
  return (unsigned short)(u >> 16);
}

__device__ __forceinline__ void load_lds16(const void* g, void* l) {
  __builtin_amdgcn_global_load_lds(
      (const __attribute__((address_space(1))) void*)g,
      (__attribute__((address_space(3))) void*)l, 16, 0, 0);
}

// One block per row (of x for row<N, of y otherwise):
//  - convert the 512-f32 row to bf16 (RNE) into workspace
//  - compute sum of squares (fp32)
//  - compute sqrt(clip(softplus(sample_row . scale)))
__global__ __launch_bounds__(256) void prep_kernel(
    const float* __restrict__ x, const float* __restrict__ y,
    const float* __restrict__ samp_x, const float* __restrict__ samp_y,
    const float* __restrict__ scale,
    ushort* __restrict__ xb, ushort* __restrict__ yb,
    float* __restrict__ sqx, float* __restrict__ sqy,
    float* __restrict__ ssx, float* __restrict__ ssy)
{
  int row = blockIdx.x;
  const float* src; const float* samp; ushort* dst; float* sqo; float* sso;
  if (row < N_ROWS) {
    src = x + (size_t)row * DDIM; samp = samp_x + (size_t)row * SDIM;
    dst = xb + (size_t)row * DDIM; sqo = sqx + row; sso = ssx + row;
  } else {
    int r = row - N_ROWS;
    src = y + (size_t)r * DDIM; samp = samp_y + (size_t)r * SDIM;
    dst = yb + (size_t)r * DDIM; sqo = sqy + r; sso = ssy + r;
  }
  int tid = threadIdx.x;  // 256 threads, 2 f32 each
  float2 v = ((const float2*)src)[tid];
  ushort2 b;
  b.x = f2bf_rne(v.x);
  b.y = f2bf_rne(v.y);
  ((ushort2*)dst)[tid] = b;
  float ss = v.x * v.x + v.y * v.y;
  #pragma unroll
  for (int off = 32; off > 0; off >>= 1) ss += __shfl_down(ss, off, 64);
  __shared__ float red[4];
  if ((tid & 63) == 0) red[tid >> 6] = ss;
  __syncthreads();
  if (tid == 0) {
    float tot = red[0] + red[1] + red[2] + red[3];
    *sqo = tot;
    float acc = 0.f;
    #pragma unroll
    for (int s = 0; s < SDIM; s++) acc += samp[s] * scale[s];
    float sp = (acc > 15.f) ? acc : log1pf(expf(acc));   // softplus
    sp = fminf(fmaxf(sp, 1e-10f), 10000.f);
    *sso = sqrtf(sp);
  }
}

// Fused GEMM + Cauchy epilogue.
// 256x256 tile, BK=32, 8 waves (2Mx4N), each wave owns a 128x64 sub-tile
// (8x4 16x16x32 frags). Triple-buffered LDS, counted-vmcnt pipeline:
// stage tile t+2 while computing tile t; s_waitcnt vmcnt(4) at tile end
// guarantees tile t+1 landed while t+2's 4 loads stay in flight across
// the barrier (never drain to 0 in the main loop).
// XOR swizzle (granule ^ (row>>1)&3) applied on BOTH global source and
// ds_read address (rule #21); LDS writes stay linear for global_load_lds.
__global__ __launch_bounds__(512, 2) void cauchy_gemm(
    const ushort* __restrict__ xb, const ushort* __restrict__ yb,
    const float* __restrict__ sqx, const float* __restrict__ sqy,
    const float* __restrict__ ssx, const float* __restrict__ ssy,
    const float* __restrict__ cutoff, const float* __restrict__ phi,
    float* __restrict__ out)
{
  __shared__ ushort As[3][BM * BK];   // 3 x 16 KiB
  __shared__ ushort Bs[3][BN * BK];   // 3 x 16 KiB  (96 KiB total)

  const int tid  = threadIdx.x;
  const int lane = tid & 63;
  const int wid  = tid >> 6;
  const int wm = wid >> 2;        // 0..1  row half
  const int wn = wid & 3;         // 0..3  col quarter
  const int l15 = lane & 15, l16 = lane >> 4;

  // bijective XCD swizzle: 512 blocks, 8 XCDs, 64 per XCD chunk
  const int bid  = blockIdx.y * 32 + blockIdx.x;
  const int sbid = (bid & 7) * 64 + (bid >> 3);
  const int bx = sbid & 31;       // N / 256 = 32 row-blocks
  const int by = sbid >> 5;       // M / 256 = 16 col-blocks

  // ---- staging geometry: 1024 granules (16B) per matrix tile, 2/thread ----
  const int g0 = tid, g1 = tid + 512;
  const int r0 = g0 >> 2, c0 = g0 & 3, s0 = c0 ^ ((r0 >> 1) & 3);
  const int r1 = g1 >> 2, c1 = g1 & 3, s1 = c1 ^ ((r1 >> 1) & 3);
  const ushort* a0 = xb + (size_t)(bx * BM + r0) * DDIM + s0 * 8;
  const ushort* a1 = xb + (size_t)(bx * BM + r1) * DDIM + s1 * 8;
  const ushort* b0 = yb + (size_t)(by * BN + r0) * DDIM + s0 * 8;
  const ushort* b1 = yb + (size_t)(by * BN + r1) * DDIM + s1 * 8;
  const int d0 = g0 * 8, d1 = g1 * 8;   // linear LDS element offsets

  // ---- fragment ds_read offsets (loop-invariant, swizzled) ----
  int aoff[8], boff[4];
  #pragma unroll
  for (int fr = 0; fr < 8; fr++) {
    int row = wm * 128 + fr * 16 + l15;
    aoff[fr] = row * BK + ((l16 ^ ((row >> 1) & 3)) << 3);
  }
  #pragma unroll
  for (int fc = 0; fc < 4; fc++) {
    int col = wn * 64 + fc * 16 + l15;
    boff[fc] = col * BK + ((l16 ^ ((col >> 1) & 3)) << 3);
  }

  f32x4 acc[8][4];
  #pragma unroll
  for (int fr = 0; fr < 8; fr++)
    #pragma unroll
    for (int fc = 0; fc < 4; fc++)
      acc[fr][fc] = (f32x4)(0.f);

  // ---- prologue: stage tiles 0 and 1, wait for tile 0 only ----
  load_lds16(a0, &As[0][d0]); load_lds16(a1, &As[0][d1]);
  load_lds16(b0, &Bs[0][d0]); load_lds16(b1, &Bs[0][d1]);
  load_lds16(a0 + BK, &As[1][d0]); load_lds16(a1 + BK, &As[1][d1]);
  load_lds16(b0 + BK, &Bs[1][d0]); load_lds16(b1 + BK, &Bs[1][d1]);
  asm volatile("s_waitcnt vmcnt(4)" ::: "memory");
  __builtin_amdgcn_s_barrier();

  int cur = 0;
  for (int t = 0; t < NT; ++t) {
    int nxt = cur + 2; if (nxt >= 3) nxt -= 3;
    if (t < NT - 2) {   // stage tile t+2 into buffer nxt (read last at t-1)
      const int k0 = (t + 2) * BK;
      load_lds16(a0 + k0, &As[nxt][d0]);
      load_lds16(a1 + k0, &As[nxt][d1]);
      load_lds16(b0 + k0, &Bs[nxt][d0]);
      load_lds16(b1 + k0, &Bs[nxt][d1]);
    }
    bf16x8 af[8], bf[4];
    #pragma unroll
    for (int fr = 0; fr < 8; fr++)
      af[fr] = *(const bf16x8*)(&As[cur][aoff[fr]]);
    #pragma unroll
    for (int fc = 0; fc < 4; fc++)
      bf[fc] = *(const bf16x8*)(&Bs[cur][boff[fc]]);

    __builtin_amdgcn_s_setprio(1);
    #pragma unroll
    for (int fr = 0; fr < 8; fr++)
      #pragma unroll
      for (int fc = 0; fc < 4; fc++)
        acc[fr][fc] = __builtin_amdgcn_mfma_f32_16x16x32_bf16(af[fr], bf[fc], acc[fr][fc], 0, 0, 0);
    __builtin_amdgcn_s_setprio(0);

    if (t < NT - 2)       asm volatile("s_waitcnt vmcnt(4)" ::: "memory"); // t+1 landed, t+2 in flight
    else if (t == NT - 2) asm volatile("s_waitcnt vmcnt(0)" ::: "memory"); // last tile landed
    __builtin_amdgcn_s_barrier();
    cur = cur + 1; if (cur >= 3) cur -= 3;
  }

  // ---- fused epilogue ----
  const float cut_c = fminf(fmaxf(cutoff[0], 0.f), 1000.f);
  const float ph = phi[0];
  const int rowBase = bx * BM + wm * 128;
  const int colBase = by * BN + wn * 64;
  const float L2E = 1.4426950408889634f;

  float sq_j[4], sy_j[4];
  #pragma unroll
  for (int fc = 0; fc < 4; fc++) {
    int j = colBase + fc * 16 + l15;
    sq_j[fc] = sqy[j];
    sy_j[fc] = ssy[j];
  }
  #pragma unroll
  for (int fr = 0; fr < 8; fr++) {
    float sq_i[4], sx_i[4];
    #pragma unroll
    for (int r = 0; r < 4; r++) {
      int i = rowBase + fr * 16 + l16 * 4 + r;
      sq_i[r] = sqx[i];
      sx_i[r] = ssx[i];
    }
    #pragma unroll
    for (int fc = 0; fc < 4; fc++) {
      #pragma unroll
      for (int r = 0; r < 4; r++) {
        int i = rowBase + fr * 16 + l16 * 4 + r;
        int j = colBase + fc * 16 + l15;
        float dot = acc[fr][fc][r];
        float d = sq_i[r] + sq_j[fc] - 2.f * dot;        // squared distance
        float s = sx_i[r] * sy_j[fc];                    // sqrt(scale_x*scale_y)
        float res = s * __builtin_amdgcn_rcpf(s + d);    // 1/(1+d/s)
        float t2 = ph * (res - cut_c);
        float u = __builtin_amdgcn_exp2f(-t2 * L2E);     // exp(-t)
        float cm = __builtin_amdgcn_rcpf(1.f + u);       // sigmoid(t)
        out[(size_t)i * M_ROWS + j] = res * cm;
      }
    }
  }
}

extern "C" void kernel_launch(void* const* d_in, const int* in_sizes, int n_in,
                              void* d_out, int out_size, void* d_ws, size_t ws_size,
                              hipStream_t stream) {
  const float* x       = (const float*)d_in[0];
  const float* y       = (const float*)d_in[1];
  const float* samp_x  = (const float*)d_in[2];
  const float* samp_y  = (const float*)d_in[3];
  const float* scale   = (const float*)d_in[4];
  const float* cutoff  = (const float*)d_in[5];
  const float* phi     = (const float*)d_in[6];
  float* out = (float*)d_out;

  char* p = (char*)d_ws;
  ushort* xb = (ushort*)p; p += (size_t)N_ROWS * DDIM * 2;
  ushort* yb = (ushort*)p; p += (size_t)M_ROWS * DDIM * 2;
  float* sqx = (float*)p;  p += (size_t)N_ROWS * 4;
  float* sqy = (float*)p;  p += (size_t)M_ROWS * 4;
  float* ssx = (float*)p;  p += (size_t)N_ROWS * 4;
  float* ssy = (float*)p;  p += (size_t)M_ROWS * 4;

  prep_kernel<<<N_ROWS + M_ROWS, 256, 0, stream>>>(
      x, y, samp_x, samp_y, scale, xb, yb, sqx, sqy, ssx, ssy);

  dim3 grid(N_ROWS / BM, M_ROWS / BN);
  cauchy_gemm<<<grid, 512, 0, stream>>>(
      xb, yb, sqx, sqy, ssx, ssy, cutoff, phi, out);
}

// Round 3
// 69.249 us; speedup vs baseline: 1.1486x; 1.1486x over previous
//
#include <hip/hip_runtime.h>
#include <hip/hip_bf16.h>
#include <math.h>

#define N_ROWS 8192
#define M_ROWS 4096
#define DDIM   512
#define SDIM   16

#define BM 256
#define BN 256
#define BK 64
#define NT (DDIM / BK)   // 8 K-tiles

typedef __attribute__((ext_vector_type(8))) __bf16 bf16x8;
typedef __attribute__((ext_vector_type(4))) float f32x4;

__device__ __forceinline__ unsigned short f2bf_rne(float f) {
  unsigned u = __float_as_uint(f);
  u += 0x7fffu + ((u >> 16) & 1u);
  return (unsigned short)(u >> 16);
}

__device__ __forceinline__ void load_lds16(const void* g, void* l) {
  __builtin_amdgcn_global_load_lds(
      (const __attribute__((address_space(1))) void*)g,
      (__attribute__((address_space(3))) void*)l, 16, 0, 0);
}

__global__ __launch_bounds__(256) void prep_kernel(
    const float* __restrict__ x, const float* __restrict__ y,
    const float* __restrict__ samp_x, const float* __restrict__ samp_y,
    const float* __restrict__ scale,
    ushort* __restrict__ xb, ushort* __restrict__ yb,
    float* __restrict__ sqx, float* __restrict__ sqy,
    float* __restrict__ ssx, float* __restrict__ ssy)
{
  int row = blockIdx.x;
  const float* src; const float* samp; ushort* dst; float* sqo; float* sso;
  if (row < N_ROWS) {
    src = x + (size_t)row * DDIM; samp = samp_x + (size_t)row * SDIM;
    dst = xb + (size_t)row * DDIM; sqo = sqx + row; sso = ssx + row;
  } else {
    int r = row - N_ROWS;
    src = y + (size_t)r * DDIM; samp = samp_y + (size_t)r * SDIM;
    dst = yb + (size_t)r * DDIM; sqo = sqy + r; sso = ssy + r;
  }
  int tid = threadIdx.x;  // 256 threads, 2 f32 each
  float2 v = ((const float2*)src)[tid];
  ushort2 b;
  b.x = f2bf_rne(v.x);
  b.y = f2bf_rne(v.y);
  ((ushort2*)dst)[tid] = b;
  float ss = v.x * v.x + v.y * v.y;
  #pragma unroll
  for (int off = 32; off > 0; off >>= 1) ss += __shfl_down(ss, off, 64);
  __shared__ float red[4];
  if ((tid & 63) == 0) red[tid >> 6] = ss;
  __syncthreads();
  if (tid == 0) {
    float tot = red[0] + red[1] + red[2] + red[3];
    *sqo = tot;
    float acc = 0.f;
    #pragma unroll
    for (int s = 0; s < SDIM; s++) acc += samp[s] * scale[s];
    float sp = (acc > 15.f) ? acc : log1pf(expf(acc));   // softplus
    sp = fminf(fmaxf(sp, 1e-10f), 10000.f);
    *sso = sqrtf(sp);
  }
}

// ---- 8-phase 256x256 GEMM (m201-style) + fused Cauchy epilogue ----
// BK=64, 8 waves (2Mx4N), wave tile 128x64 (8x4 frags of 16x16).
// LDS: 2 bufs x (A 32K + B 32K) = 128 KiB, 1 block/CU.
// Per K-tile: 4 phases, each {ds_read quadrant | stage 1 half-tile (2 gload_lds)
//   -> barrier -> setprio+16 MFMA -> barrier}; vmcnt(2) once per tile, placed
//   BEFORE the tile-crossing barrier (per-wave vmcnt + barrier = cross-wave sync).
// Stage schedule (tile t phases C1..C4): C1: Ah1(t+1), C2: Bh0(t+1),
//   C3: Bh1(t+1), C4: Ah0(t+2). Every overwrite is >=1 full barrier-phase
//   after the last read of that LDS region (A reads end C3, B LDS reads end C2).
// XOR swizzle (granule ^ (row&7)) on BOTH global source and ds_read address.

#define STG(SRC, ARR, bufi, h, kt)                                              \
  do {                                                                          \
    load_lds16((SRC) + (size_t)((h) * 128) * DDIM + (kt) * BK,                  \
               &ARR[bufi][(h) * 8192 + ldsoff]);                                \
    load_lds16((SRC) + (size_t)((h) * 128 + 64) * DDIM + (kt) * BK,             \
               &ARR[bufi][(h) * 8192 + 4096 + ldsoff]);                         \
  } while (0)

#define RDA(QR)                                                                 \
  _Pragma("unroll") for (int i = 0; i < 4; i++)                                 \
  _Pragma("unroll") for (int kk = 0; kk < 2; kk++)                              \
    af[i][kk] = *(const bf16x8*)&Ab[(wm * 128 + ((QR) * 4 + i) * 16 + l15) * BK \
                                    + (((kk * 4 + l16) ^ s7) << 3)];

#define RDB(QC, D)                                                              \
  _Pragma("unroll") for (int j = 0; j < 2; j++)                                 \
  _Pragma("unroll") for (int kk = 0; kk < 2; kk++)                              \
    D[j][kk] = *(const bf16x8*)&Bb[(wn * 64 + ((QC) * 2 + j) * 16 + l15) * BK   \
                                   + (((kk * 4 + l16) ^ s7) << 3)];

#define MFMA16(AF, BF, R0, C0)                                                  \
  __builtin_amdgcn_s_setprio(1);                                                \
  _Pragma("unroll") for (int i = 0; i < 4; i++)                                 \
  _Pragma("unroll") for (int j = 0; j < 2; j++)                                 \
  _Pragma("unroll") for (int kk = 0; kk < 2; kk++)                              \
    acc[(R0) + i][(C0) + j] = __builtin_amdgcn_mfma_f32_16x16x32_bf16(          \
        AF[i][kk], BF[j][kk], acc[(R0) + i][(C0) + j], 0, 0, 0);                \
  __builtin_amdgcn_s_setprio(0);

__global__ __launch_bounds__(512, 2) void cauchy_gemm(
    const ushort* __restrict__ xb, const ushort* __restrict__ yb,
    const float* __restrict__ sqx, const float* __restrict__ sqy,
    const float* __restrict__ ssx, const float* __restrict__ ssy,
    const float* __restrict__ cutoff, const float* __restrict__ phi,
    float* __restrict__ out)
{
  __shared__ ushort As[2][BM * BK];   // 2 x 32 KiB
  __shared__ ushort Bs[2][BN * BK];   // 2 x 32 KiB

  const int tid  = threadIdx.x;
  const int lane = tid & 63;
  const int wid  = tid >> 6;
  const int wm = wid >> 2;        // 0..1
  const int wn = wid & 3;         // 0..3
  const int l15 = lane & 15, l16 = lane >> 4;
  const int s7 = l15 & 7;

  // bijective XCD swizzle: 512 blocks = 8 XCDs x (8x8 tile chunk)
  const int bid = blockIdx.x;
  const int xcd = bid & 7, loc = bid >> 3;
  const int bx = (xcd & 3) * 8 + (loc & 7);    // 32 row-blocks
  const int by = (xcd >> 2) * 8 + (loc >> 3);  // 16 col-blocks

  // staging geometry: thread covers granule (rr, gg) of rows [0,64) per q-step
  const int rr = tid >> 3, gg = tid & 7;
  const int sg8 = ((gg ^ (rr & 7)) << 3);      // pre-swizzled source granule
  const int ldsoff = rr * 64 + (gg << 3);      // linear LDS dest (elements)
  const ushort* aSrc = xb + (size_t)(bx * BM + rr) * DDIM + sg8;
  const ushort* bSrc = yb + (size_t)(by * BN + rr) * DDIM + sg8;

  f32x4 acc[8][4];
  #pragma unroll
  for (int i = 0; i < 8; i++)
    #pragma unroll
    for (int j = 0; j < 4; j++) acc[i][j] = (f32x4)(0.f);

  bf16x8 af[4][2], bfa[2][2], bfb[2][2];

  // ---- prologue: tile0 (all 4 halves) + Ah0(tile1); keep tile1's A-h0 in flight
  STG(aSrc, As, 0, 0, 0); STG(aSrc, As, 0, 1, 0);
  STG(bSrc, Bs, 0, 0, 0); STG(bSrc, Bs, 0, 1, 0);
  STG(aSrc, As, 1, 0, 1);
  asm volatile("s_waitcnt vmcnt(2)" ::: "memory");
  __builtin_amdgcn_s_barrier();

  #pragma unroll
  for (int t = 0; t < NT; ++t) {
    const int b = t & 1, nb = b ^ 1;
    const ushort* Ab = As[b];
    const ushort* Bb = Bs[b];
    // ---- C1: quadrant (rows 0-3, cols 0-1) ----
    RDA(0)
    RDB(0, bfa)
    if (t + 1 < NT) STG(aSrc, As, nb, 1, t + 1);     // Ah1(t+1)
    __builtin_amdgcn_s_barrier();
    MFMA16(af, bfa, 0, 0)
    __builtin_amdgcn_s_barrier();
    // ---- C2: (rows 0-3, cols 2-3) ----
    RDB(1, bfb)
    if (t + 1 < NT) STG(bSrc, Bs, nb, 0, t + 1);     // Bh0(t+1)
    __builtin_amdgcn_s_barrier();
    MFMA16(af, bfb, 0, 2)
    __builtin_amdgcn_s_barrier();
    // ---- C3: (rows 4-7, cols 2-3) ----
    RDA(1)
    if (t + 1 < NT) STG(bSrc, Bs, nb, 1, t + 1);     // Bh1(t+1)
    __builtin_amdgcn_s_barrier();
    MFMA16(af, bfb, 4, 2)
    __builtin_amdgcn_s_barrier();
    // ---- C4: (rows 4-7, cols 0-1), bfa register-held from C1 ----
    if (t + 2 < NT) STG(aSrc, As, b, 0, t + 2);      // Ah0(t+2)
    __builtin_amdgcn_s_barrier();
    MFMA16(af, bfa, 4, 0)
    if (t + 2 < NT) asm volatile("s_waitcnt vmcnt(2)" ::: "memory");
    else            asm volatile("s_waitcnt vmcnt(0)" ::: "memory");
    __builtin_amdgcn_s_barrier();   // tile t+1 fully landed for ALL waves
  }

  // ---- fused epilogue ----
  const float cut_c = fminf(fmaxf(cutoff[0], 0.f), 1000.f);
  const float ph = phi[0];
  const int rowBase = bx * BM + wm * 128;
  const int colBase = by * BN + wn * 64;
  const float L2E = 1.4426950408889634f;

  float sq_j[4], sy_j[4];
  #pragma unroll
  for (int fc = 0; fc < 4; fc++) {
    int j = colBase + fc * 16 + l15;
    sq_j[fc] = sqy[j];
    sy_j[fc] = ssy[j];
  }
  #pragma unroll
  for (int fr = 0; fr < 8; fr++) {
    float sq_i[4], sx_i[4];
    #pragma unroll
    for (int r = 0; r < 4; r++) {
      int i = rowBase + fr * 16 + l16 * 4 + r;
      sq_i[r] = sqx[i];
      sx_i[r] = ssx[i];
    }
    #pragma unroll
    for (int fc = 0; fc < 4; fc++) {
      #pragma unroll
      for (int r = 0; r < 4; r++) {
        int i = rowBase + fr * 16 + l16 * 4 + r;
        int j = colBase + fc * 16 + l15;
        float dot = acc[fr][fc][r];
        float d = sq_i[r] + sq_j[fc] - 2.f * dot;        // squared distance
        float s = sx_i[r] * sy_j[fc];                    // sqrt(scale_x*scale_y)
        float res = s * __builtin_amdgcn_rcpf(s + d);    // 1/(1+d/s)
        float t2 = ph * (res - cut_c);
        float u = __builtin_amdgcn_exp2f(-t2 * L2E);     // exp(-t)
        float cm = __builtin_amdgcn_rcpf(1.f + u);       // sigmoid(t)
        out[(size_t)i * M_ROWS + j] = res * cm;
      }
    }
  }
}

extern "C" void kernel_launch(void* const* d_in, const int* in_sizes, int n_in,
                              void* d_out, int out_size, void* d_ws, size_t ws_size,
                              hipStream_t stream) {
  const float* x       = (const float*)d_in[0];
  const float* y       = (const float*)d_in[1];
  const float* samp_x  = (const float*)d_in[2];
  const float* samp_y  = (const float*)d_in[3];
  const float* scale   = (const float*)d_in[4];
  const float* cutoff  = (const float*)d_in[5];
  const float* phi     = (const float*)d_in[6];
  float* out = (float*)d_out;

  char* p = (char*)d_ws;
  ushort* xb = (ushort*)p; p += (size_t)N_ROWS * DDIM * 2;
  ushort* yb = (ushort*)p; p += (size_t)M_ROWS * DDIM * 2;
  float* sqx = (float*)p;  p += (size_t)N_ROWS * 4;
  float* sqy = (float*)p;  p += (size_t)M_ROWS * 4;
  float* ssx = (float*)p;  p += (size_t)N_ROWS * 4;
  float* ssy = (float*)p;  p += (size_t)M_ROWS * 4;

  prep_kernel<<<N_ROWS + M_ROWS, 256, 0, stream>>>(
      x, y, samp_x, samp_y, scale, xb, yb, sqx, sqy, ssx, ssy);

  cauchy_gemm<<<(N_ROWS / BM) * (M_ROWS / BN), 512, 0, stream>>>(
      xb, yb, sqx, sqy, ssx, ssy, cutoff, phi, out);
}